// Round 5
// baseline (1655.843 us; speedup 1.0000x reference)
//
#include <hip/hip_runtime.h>

// FeatureExpansion: per (b, ol) stride of 10x32 f32 -> 1120 f32 outputs
// [std(32) | z(32) | ld(32) | ret(32) | covf(496) | corrf(496)]
// One wave per stride; 4 waves per block; wave-local sync only.
// No LDS staging of outputs: cov/corr tile rows are contiguous in packed-p
// space, so they are stored straight from registers; L2 merges the lines
// (all stores land in the stride's own contiguous 4480B window).

typedef float fx4  __attribute__((ext_vector_type(4)));
typedef float fx4u __attribute__((ext_vector_type(4), aligned(4)));  // 4B-aligned vector stores
typedef float fx3u __attribute__((ext_vector_type(3), aligned(4)));
typedef float fx2u __attribute__((ext_vector_type(2), aligned(4)));

constexpr int S      = 10;
constexpr int F      = 32;
constexpr int NPAIR  = 496;     // F*(F-1)/2
constexpr int OUTW   = 1120;    // 4*F + 2*NPAIR
constexpr int WAVES  = 4;
// per-wave LDS slice (floats): raw[320] | mu[32] | rs[32]
constexpr int SLICE  = 320 + 64;   // 384 floats = 1536 B

// Wave-local barrier (each wave touches only its own LDS slice).
__device__ __forceinline__ void wave_sync() {
    asm volatile("s_waitcnt lgkmcnt(0)" ::: "memory");
    __builtin_amdgcn_sched_barrier(0);
}
__device__ __forceinline__ float fast_rcp(float x) { return __builtin_amdgcn_rcpf(x); }

__global__ __launch_bounds__(256, 8)
void fe_kernel(const float* __restrict__ in, float* __restrict__ out, int nstrides)
{
    __shared__ float lds[WAVES * SLICE];

    const int wv   = threadIdx.x >> 6;
    const int lane = threadIdx.x & 63;
    int sid = blockIdx.x * WAVES + wv;
    if (sid >= nstrides) sid = nstrides - 1;   // grid divides exactly for this shape

    float* raw = &lds[wv * SLICE];   // 10x32 raw tile
    float* muv = raw + 320;          // mean per feature
    float* rsv = raw + 352;          // rcp(std) per feature (0 where std==0)

    const float* src = in  + (size_t)sid * (S * F);
    float*       dst = out + (size_t)sid * OUTW;

    // ---- P1: global -> LDS (2 vector loads, coalesced, streamed) ----
    {
        fx4 v0 = __builtin_nontemporal_load((const fx4*)(src + 4 * lane));
        *(fx4*)(raw + 4 * lane) = v0;
        if (lane < 16) {
            fx4 v1 = __builtin_nontemporal_load((const fx4*)(src + 256 + 4 * lane));
            *(fx4*)(raw + 256 + 4 * lane) = v1;
        }
    }
    wave_sync();

    const int f    = lane & 31;
    const int half = lane >> 5;

    // ---- P2: one 10-read pass -> mean/std/z (half 0), ld/ret (half 1);
    //          std/z/ld/ret go straight to global ----
    {
        float sum = 0.f, sumsq = 0.f, ldacc = 0.f, first = 0.f, last = 0.f;
        #pragma unroll
        for (int s = 0; s < S; ++s) {
            float v = raw[s * F + f];          // halves read same addrs (2-way broadcast)
            sum   += v;
            sumsq += v * v;
            ldacc += (float)(s + 1) * v;
            if (s == 0)     first = v;
            if (s == S - 1) last  = v;
        }
        if (half == 0) {
            float mean = sum * 0.1f;
            float var  = fmaxf(sumsq * 0.1f - mean * mean, 0.0f);  // biased var
            float sd   = __builtin_amdgcn_sqrtf(var);
            float rs   = (sd == 0.0f) ? 0.0f : fast_rcp(sd);
            muv[f] = mean;
            rsv[f] = rs;
            dst[f]     = sd;          // std
            dst[F + f] = mean * rs;   // z = divide_no_nan(mean, std)
        } else {
            dst[2 * F + f] = ldacc * (1.0f / 55.0f);   // linspace(1,10)/55
            float ret = (first == 0.0f) ? 0.0f : last * fast_rcp(first);
            dst[3 * F + f] = ret - 1.0f;
        }
    }
    wave_sync();

    // ---- P5: pairwise products on RAW data; acc init = -10*mu_r*mu_c;
    //          results stored straight to global, vectorized per tile row ----
    {
        const int rb = lane >> 3;   // 0..7
        const int cb = lane & 7;    // 0..7
        fx4 ma = *(fx4*)(muv + 4 * rb);
        fx4 mb = *(fx4*)(muv + 4 * cb);
        fx4 ra = *(fx4*)(rsv + 4 * rb);
        fx4 rc = *(fx4*)(rsv + 4 * cb);
        const float maa[4] = {ma.x, ma.y, ma.z, ma.w};
        const float mbb[4] = {mb.x, mb.y, mb.z, mb.w};
        const float raa[4] = {ra.x, ra.y, ra.z, ra.w};
        const float rcc[4] = {rc.x, rc.y, rc.z, rc.w};

        float acc[4][4];
        #pragma unroll
        for (int i = 0; i < 4; ++i) {
            float nm = -10.0f * maa[i];
            #pragma unroll
            for (int j = 0; j < 4; ++j) acc[i][j] = nm * mbb[j];
        }

        #pragma unroll
        for (int s = 0; s < S; ++s) {
            fx4 a4 = *(fx4*)(raw + s * F + 4 * rb);   // 8 distinct addrs -> broadcast
            fx4 b4 = *(fx4*)(raw + s * F + 4 * cb);
            const float aa[4] = {a4.x, a4.y, a4.z, a4.w};
            const float bb[4] = {b4.x, b4.y, b4.z, b4.w};
            #pragma unroll
            for (int i = 0; i < 4; ++i)
                #pragma unroll
                for (int j = 0; j < 4; ++j)
                    acc[i][j] += aa[i] * bb[j];
        }

        float* covd = dst + 4 * F;            // 496 packed lower-tri
        float* cord = dst + 4 * F + NPAIR;    // 496 packed lower-tri

        if (rb > cb) {
            // full lower tile: each row = 4 consecutive packed indices
            #pragma unroll
            for (int i = 0; i < 4; ++i) {
                const int r = 4 * rb + i;
                const int p = (r * (r - 1)) / 2 + 4 * cb;
                fx4u cv = { acc[i][0], acc[i][1], acc[i][2], acc[i][3] };
                cv *= (1.0f / 9.0f);
                *(fx4u*)(covd + p) = cv;
                const float sc = 0.1f * raa[i];
                fx4u cr = { acc[i][0] * rcc[0], acc[i][1] * rcc[1],
                            acc[i][2] * rcc[2], acc[i][3] * rcc[3] };
                cr *= sc;
                *(fx4u*)(cord + p) = cr;
            }
        } else if (rb == cb) {
            const int base = 4 * rb;
            {   // row i=1: 1 element (c = base)
                const int r = base + 1;
                const int p = (r * (r - 1)) / 2 + base;
                covd[p] = acc[1][0] * (1.0f / 9.0f);
                cord[p] = acc[1][0] * 0.1f * raa[1] * rcc[0];
            }
            {   // row i=2: 2 elements
                const int r = base + 2;
                const int p = (r * (r - 1)) / 2 + base;
                fx2u cv = { acc[2][0], acc[2][1] };
                cv *= (1.0f / 9.0f);
                *(fx2u*)(covd + p) = cv;
                const float sc = 0.1f * raa[2];
                fx2u cr = { acc[2][0] * rcc[0], acc[2][1] * rcc[1] };
                cr *= sc;
                *(fx2u*)(cord + p) = cr;
            }
            {   // row i=3: 3 elements
                const int r = base + 3;
                const int p = (r * (r - 1)) / 2 + base;
                fx3u cv = { acc[3][0], acc[3][1], acc[3][2] };
                cv *= (1.0f / 9.0f);
                *(fx3u*)(covd + p) = cv;
                const float sc = 0.1f * raa[3];
                fx3u cr = { acc[3][0] * rcc[0], acc[3][1] * rcc[1], acc[3][2] * rcc[2] };
                cr *= sc;
                *(fx3u*)(cord + p) = cr;
            }
        }
        // rb < cb: upper-triangle tile, nothing to store
    }
}

extern "C" void kernel_launch(void* const* d_in, const int* in_sizes, int n_in,
                              void* d_out, int out_size, void* d_ws, size_t ws_size,
                              hipStream_t stream)
{
    const float* in = (const float*)d_in[0];
    float* out      = (float*)d_out;
    const int nstrides = in_sizes[0] / (S * F);          // 122880
    const int grid     = (nstrides + WAVES - 1) / WAVES; // 30720
    fe_kernel<<<grid, 256, 0, stream>>>(in, out, nstrides);
}

// Round 6
// 1433.288 us; speedup vs baseline: 1.1553x; 1.1553x over previous
//
#include <hip/hip_runtime.h>

// FeatureExpansion: per (b, ol) stride of 10x32 f32 -> 1120 f32 outputs
// [std(32) | z(32) | ld(32) | ret(32) | covf(496) | corrf(496)]
// One wave per stride; 4 waves per block; wave-local sync only.
// cov/corr staged in LDS for coalesced writeout (R5 lesson: scattered global
// stores cause 10x RMW traffic amplification). std/z/ld/ret stored direct
// (they are full-line contiguous per masked instruction).

typedef float fx4  __attribute__((ext_vector_type(4)));
typedef float fx4u __attribute__((ext_vector_type(4), aligned(4)));
typedef float fx3u __attribute__((ext_vector_type(3), aligned(4)));
typedef float fx2u __attribute__((ext_vector_type(2), aligned(4)));

constexpr int S      = 10;
constexpr int F      = 32;
constexpr int NPAIR  = 496;     // F*(F-1)/2
constexpr int OUTW   = 1120;    // 4*F + 2*NPAIR
constexpr int WAVES  = 4;
// per-wave LDS slice (floats): raw[320] | mu[32] | rs[32] | stage[992]
constexpr int SLICE  = 320 + 64 + 2 * NPAIR;   // 1376 floats = 5504 B (16B aligned)

// Wave-local barrier (each wave touches only its own LDS slice).
__device__ __forceinline__ void wave_sync() {
    asm volatile("s_waitcnt lgkmcnt(0)" ::: "memory");
    __builtin_amdgcn_sched_barrier(0);
}
__device__ __forceinline__ float fast_rcp(float x) { return __builtin_amdgcn_rcpf(x); }

__global__ __launch_bounds__(256, 7)
void fe_kernel(const float* __restrict__ in, float* __restrict__ out, int nstrides)
{
    __shared__ float lds[WAVES * SLICE];

    const int wv   = threadIdx.x >> 6;
    const int lane = threadIdx.x & 63;
    int sid = blockIdx.x * WAVES + wv;
    if (sid >= nstrides) sid = nstrides - 1;   // grid divides exactly for this shape

    float* raw   = &lds[wv * SLICE];   // 10x32 raw tile
    float* muv   = raw + 320;          // mean per feature
    float* rsv   = raw + 352;          // rcp(std) per feature (0 where std==0)
    float* stage = raw + 384;          // covf[496] | corrf[496]

    const float* src = in  + (size_t)sid * (S * F);
    float*       dst = out + (size_t)sid * OUTW;

    // ---- P1: global -> LDS (2 vector loads, coalesced, streamed) ----
    {
        fx4 v0 = __builtin_nontemporal_load((const fx4*)(src + 4 * lane));
        *(fx4*)(raw + 4 * lane) = v0;
        if (lane < 16) {
            fx4 v1 = __builtin_nontemporal_load((const fx4*)(src + 256 + 4 * lane));
            *(fx4*)(raw + 256 + 4 * lane) = v1;
        }
    }
    wave_sync();

    const int f    = lane & 31;
    const int half = lane >> 5;

    // ---- P2: one 10-read pass; std/z/ld/ret stored DIRECT (full-line segments) ----
    {
        float sum = 0.f, sumsq = 0.f, ldacc = 0.f, first = 0.f, last = 0.f;
        #pragma unroll
        for (int s = 0; s < S; ++s) {
            float v = raw[s * F + f];          // halves read same addrs (broadcast)
            sum   += v;
            sumsq += v * v;
            ldacc += (float)(s + 1) * v;
            if (s == 0)     first = v;
            if (s == S - 1) last  = v;
        }
        if (half == 0) {
            float mean = sum * 0.1f;
            float var  = fmaxf(sumsq * 0.1f - mean * mean, 0.0f);  // biased var
            float sd   = __builtin_amdgcn_sqrtf(var);
            float rs   = (sd == 0.0f) ? 0.0f : fast_rcp(sd);
            muv[f] = mean;
            rsv[f] = rs;
            __builtin_nontemporal_store(sd,        dst + f);        // std  [0..31]
            __builtin_nontemporal_store(mean * rs, dst + F + f);    // z    [32..63]
        } else {
            __builtin_nontemporal_store(ldacc * (1.0f / 55.0f), dst + 2 * F + f);  // ld
            float ret = (first == 0.0f) ? 0.0f : last * fast_rcp(first);
            __builtin_nontemporal_store(ret - 1.0f, dst + 3 * F + f);              // ret
        }
    }
    wave_sync();

    // ---- P5: pairwise products on RAW data; acc init = -10*mu_r*mu_c ----
    {
        const int rb = lane >> 3;   // 0..7
        const int cb = lane & 7;    // 0..7
        fx4 ma = *(fx4*)(muv + 4 * rb);
        fx4 mb = *(fx4*)(muv + 4 * cb);
        fx4 ra = *(fx4*)(rsv + 4 * rb);
        fx4 rc = *(fx4*)(rsv + 4 * cb);
        const float maa[4] = {ma.x, ma.y, ma.z, ma.w};
        const float mbb[4] = {mb.x, mb.y, mb.z, mb.w};
        const float raa[4] = {ra.x, ra.y, ra.z, ra.w};
        const float rcc[4] = {rc.x, rc.y, rc.z, rc.w};

        float acc[4][4];
        #pragma unroll
        for (int i = 0; i < 4; ++i) {
            float nm = -10.0f * maa[i];
            #pragma unroll
            for (int j = 0; j < 4; ++j) acc[i][j] = nm * mbb[j];
        }

        #pragma unroll
        for (int s = 0; s < S; ++s) {
            fx4 a4 = *(fx4*)(raw + s * F + 4 * rb);   // 8 distinct addrs -> broadcast
            fx4 b4 = *(fx4*)(raw + s * F + 4 * cb);
            const float aa[4] = {a4.x, a4.y, a4.z, a4.w};
            const float bb[4] = {b4.x, b4.y, b4.z, b4.w};
            #pragma unroll
            for (int i = 0; i < 4; ++i)
                #pragma unroll
                for (int j = 0; j < 4; ++j)
                    acc[i][j] += aa[i] * bb[j];
        }

        float* stgc = stage;            // cov packed lower-tri
        float* stgr = stage + NPAIR;    // corr packed lower-tri

        if (rb > cb) {
            // full lower tile: each row = 4 consecutive packed indices -> wide LDS writes
            #pragma unroll
            for (int i = 0; i < 4; ++i) {
                const int r = 4 * rb + i;
                const int p = (r * (r - 1)) / 2 + 4 * cb;
                fx4u cv = { acc[i][0], acc[i][1], acc[i][2], acc[i][3] };
                *(fx4u*)(stgc + p) = cv * (1.0f / 9.0f);
                const float sc = 0.1f * raa[i];
                fx4u cr = { acc[i][0] * rcc[0], acc[i][1] * rcc[1],
                            acc[i][2] * rcc[2], acc[i][3] * rcc[3] };
                *(fx4u*)(stgr + p) = cr * sc;
            }
        } else if (rb == cb) {
            const int base = 4 * rb;
            {   // row 1: 1 element
                const int r = base + 1;
                const int p = (r * (r - 1)) / 2 + base;
                stgc[p] = acc[1][0] * (1.0f / 9.0f);
                stgr[p] = acc[1][0] * 0.1f * raa[1] * rcc[0];
            }
            {   // row 2: 2 elements
                const int r = base + 2;
                const int p = (r * (r - 1)) / 2 + base;
                fx2u cv = { acc[2][0], acc[2][1] };
                *(fx2u*)(stgc + p) = cv * (1.0f / 9.0f);
                const float sc = 0.1f * raa[2];
                fx2u cr = { acc[2][0] * rcc[0], acc[2][1] * rcc[1] };
                *(fx2u*)(stgr + p) = cr * sc;
            }
            {   // row 3: 3 elements
                const int r = base + 3;
                const int p = (r * (r - 1)) / 2 + base;
                fx3u cv = { acc[3][0], acc[3][1], acc[3][2] };
                *(fx3u*)(stgc + p) = cv * (1.0f / 9.0f);
                const float sc = 0.1f * raa[3];
                fx3u cr = { acc[3][0] * rcc[0], acc[3][1] * rcc[1], acc[3][2] * rcc[2] };
                *(fx3u*)(stgr + p) = cr * sc;
            }
        }
        // rb < cb: upper-triangle tile, nothing to store
    }
    wave_sync();

    // ---- P6: coalesced streamed writeout of cov/corr: 248 float4 per stride ----
    {
        float* dstc = dst + 4 * F;   // 16B-aligned (512B offset into 64B-aligned stride)
        #pragma unroll
        for (int k = 0; k < 4; ++k) {
            int idx4 = lane + 64 * k;
            if (idx4 < (2 * NPAIR) / 4) {           // 248
                fx4 v = *(fx4*)(stage + 4 * idx4);  // 16B-aligned LDS read
                __builtin_nontemporal_store(v, (fx4*)(dstc + 4 * idx4));
            }
        }
    }
}

extern "C" void kernel_launch(void* const* d_in, const int* in_sizes, int n_in,
                              void* d_out, int out_size, void* d_ws, size_t ws_size,
                              hipStream_t stream)
{
    const float* in = (const float*)d_in[0];
    float* out      = (float*)d_out;
    const int nstrides = in_sizes[0] / (S * F);          // 122880
    const int grid     = (nstrides + WAVES - 1) / WAVES; // 30720
    fe_kernel<<<grid, 256, 0, stream>>>(in, out, nstrides);
}